// Round 1
// baseline (1055.450 us; speedup 1.0000x reference)
//
#include <hip/hip_runtime.h>
#include <stdint.h>

// ---------------------------------------------------------------------------
// ConditionedCTKoopmanTransition: d=512, u=32, n_obs=50, B=512, T=256
// Plan:
//   1. Augmented matrix Maug = [[A_ct, B_ct],[0,0]] * dt, padded to 576.
//      expm via scaling (s=5) + degree-11 Paterson-Stockmeyer Taylor.
//      GEMMs use split-bf16 (hi+lo) 3-product MFMA => ~f32 precision.
//   2. A_bar = top-left, B_bar = top-right of expm.
//   3. Chunked scan, L=16: Z_{t0+j} = Z0*(A^T)^j + sum_i U_i * (A^{j-i} B)^T
//      => one GEMM per chunk: [Z0|U_1..16](512x1024) @ WbigT^T(1024x8192).
//   4. Y = Z@C^T + (dt*U)@D^T as a separate bf16-MFMA pass.
// ---------------------------------------------------------------------------

typedef __bf16 bf16x8 __attribute__((ext_vector_type(8)));
typedef float  f32x4  __attribute__((ext_vector_type(4)));

#define NE  576
#define NE3 1728   // 3*NE (split-bf16: [hi|hi|lo] x [hi|lo|hi])

__device__ __forceinline__ unsigned short f2bf(float x){
  union { float f; unsigned int u; } v; v.f = x;
  unsigned int r = (v.u + 0x7fffu + ((v.u >> 16) & 1u)) >> 16;
  return (unsigned short)r;
}
__device__ __forceinline__ float bf2f(unsigned short h){
  union { float f; unsigned int u; } v; v.u = ((unsigned int)h) << 16;
  return v.f;
}

__device__ __forceinline__ void gll16(const void* g, void* l){
  __builtin_amdgcn_global_load_lds((__attribute__((address_space(1))) void*)g,
                                   (__attribute__((address_space(3))) void*)l,
                                   16, 0, 0);
}

// ---------------------------------------------------------------------------
// build scaled augmented matrix X = Maug * dt / 32, f32 + split forms
// ---------------------------------------------------------------------------
__global__ __launch_bounds__(256) void k_build_M(
    const float* __restrict__ skew, const float* __restrict__ gamma,
    const float* __restrict__ dtp, const float* __restrict__ B_ct,
    float* __restrict__ Xf, unsigned short* __restrict__ XAp,
    unsigned short* __restrict__ XBt){
  int id = blockIdx.x * 256 + threadIdx.x;
  if (id >= NE * NE) return;
  int r = id / NE, c = id % NE;
  float sc = dtp[0] * (1.0f / 32.0f);
  float v = 0.f;
  if (r < 512 && c < 512) {
    if (r < c) {
      long k = 511L * r - (long)r * (r - 1) / 2 + (c - r - 1);
      v = skew[k];
    } else if (r > c) {
      long k = 511L * c - (long)c * (c - 1) / 2 + (r - c - 1);
      v = -skew[k];
    } else {
      float g = gamma[r];
      float sp = (g > 20.f) ? g : log1pf(expf(g));
      v = -sp;
    }
  } else if (r < 512 && c >= 512 && c < 544) {
    v = B_ct[r * 32 + (c - 512)];
  }
  v *= sc;
  Xf[id] = v;
  unsigned short hi = f2bf(v);
  unsigned short lo = f2bf(v - bf2f(hi));
  XAp[(long)r * NE3 + c]          = hi;
  XAp[(long)r * NE3 + NE + c]     = hi;
  XAp[(long)r * NE3 + 2 * NE + c] = lo;
  XBt[(long)c * NE3 + r]          = hi;
  XBt[(long)c * NE3 + NE + r]     = lo;
  XBt[(long)c * NE3 + 2 * NE + r] = hi;
}

// ---------------------------------------------------------------------------
// split-bf16 GEMM for expm: C(576x576) = A*B (+Cadd), K=1728 over split forms
// BM=BN=32, 4 waves (2x2), one 16x16 frag per wave
// ---------------------------------------------------------------------------
__global__ __launch_bounds__(256) void k_expm_gemm(
    const unsigned short* __restrict__ Ap, const unsigned short* __restrict__ Bt,
    const float* __restrict__ Cadd, float* __restrict__ outF,
    unsigned short* __restrict__ outAp, unsigned short* __restrict__ outBt){
  __shared__ __align__(16) unsigned short As[32 * 32];
  __shared__ __align__(16) unsigned short Bs[32 * 32];
  int tid = threadIdx.x, wave = tid >> 6, lane = tid & 63;
  int wm = wave & 1, wn = wave >> 1;
  int m0 = blockIdx.y * 32, n0 = blockIdx.x * 32;
  int lr = lane & 15, kq = lane >> 4;
  f32x4 acc = {0.f, 0.f, 0.f, 0.f};
  for (int kt = 0; kt < NE3; kt += 32) {
    __syncthreads();
    // A tile: 32 rows x 32 k = 128 chunks of 16B -> waves 0,1
    for (int base = wave * 64; base < 128; base += 256) {
      int cc = base + lane; int rr = cc >> 2, k8 = (cc & 3) << 3;
      gll16(Ap + (long)(m0 + rr) * NE3 + kt + k8, As + base * 8);
    }
    // B tile -> waves 2,3
    for (int base = (wave ^ 2) * 64; base < 128; base += 256) {
      int cc = base + lane; int rr = cc >> 2, k8 = (cc & 3) << 3;
      gll16(Bt + (long)(n0 + rr) * NE3 + kt + k8, Bs + base * 8);
    }
    __syncthreads();
    bf16x8 af = *(const bf16x8*)&As[(wm * 16 + lr) * 32 + kq * 8];
    bf16x8 bf = *(const bf16x8*)&Bs[(wn * 16 + lr) * 32 + kq * 8];
    acc = __builtin_amdgcn_mfma_f32_16x16x32_bf16(af, bf, acc, 0, 0, 0);
  }
  int n = n0 + wn * 16 + lr;
  for (int i = 0; i < 4; i++) {
    int m = m0 + wm * 16 + kq * 4 + i;
    float v = acc[i];
    if (Cadd) v += Cadd[(long)m * NE + n];
    if (outF) outF[(long)m * NE + n] = v;
    unsigned short hi = f2bf(v);
    unsigned short lo = f2bf(v - bf2f(hi));
    if (outAp) {
      outAp[(long)m * NE3 + n]          = hi;
      outAp[(long)m * NE3 + NE + n]     = hi;
      outAp[(long)m * NE3 + 2 * NE + n] = lo;
    }
    if (outBt) {
      outBt[(long)n * NE3 + m]          = hi;
      outBt[(long)n * NE3 + NE + m]     = lo;
      outBt[(long)n * NE3 + 2 * NE + m] = hi;
    }
  }
}

// ---------------------------------------------------------------------------
// Paterson-Stockmeyer coefficient matrices B0,B1 (f32) and B2 (split Ap)
// ---------------------------------------------------------------------------
__global__ __launch_bounds__(256) void k_poly(
    const float* __restrict__ Xf, const float* __restrict__ X2f,
    const float* __restrict__ X3f, float* __restrict__ B0,
    float* __restrict__ B1, unsigned short* __restrict__ B2Ap){
  int id = blockIdx.x * 256 + threadIdx.x;
  if (id >= NE * NE) return;
  int r = id / NE, c = id % NE;
  float x = Xf[id], x2 = X2f[id], x3 = X3f[id];
  float ii = (r == c) ? 1.f : 0.f;
  float b0 = ii + x + x2 * 0.5f + x3 * (1.f / 6.f);
  float b1 = ii * (1.f / 24.f) + x * (1.f / 120.f) + x2 * (1.f / 720.f) + x3 * (1.f / 5040.f);
  float b2 = ii * (1.f / 40320.f) + x * (1.f / 362880.f) + x2 * (1.f / 3628800.f) + x3 * (1.f / 39916800.f);
  B0[id] = b0; B1[id] = b1;
  unsigned short hi = f2bf(b2), lo = f2bf(b2 - bf2f(hi));
  B2Ap[(long)r * NE3 + c]          = hi;
  B2Ap[(long)r * NE3 + NE + c]     = hi;
  B2Ap[(long)r * NE3 + 2 * NE + c] = lo;
}

// ---------------------------------------------------------------------------
// extract A_bar/B_bar from expm result, build bf16 operands
// ---------------------------------------------------------------------------
__global__ __launch_bounds__(256) void k_extract(
    const float* __restrict__ F, const float* __restrict__ Cin,
    const float* __restrict__ Din, const float* __restrict__ dtp,
    unsigned short* __restrict__ WbigT, unsigned short* __restrict__ PT1,
    unsigned short* __restrict__ BbarT, unsigned short* __restrict__ G0,
    unsigned short* __restrict__ Cbf, unsigned short* __restrict__ Ddt){
  long id = (long)blockIdx.x * 256 + threadIdx.x;
  if (id < 512 * 512) {
    int m = (int)(id >> 9), k = (int)(id & 511);
    WbigT[(long)m * 1024 + k] = f2bf(F[(long)m * NE + k]);   // Apow_1 row-major
    PT1[id] = f2bf(F[(long)k * NE + m]);                      // (A^T)
  }
  if (id < 512 * 32) {
    int dd = (int)(id >> 5), u = (int)(id & 31);
    unsigned short h = f2bf(F[(long)dd * NE + 512 + u]);
    G0[id] = h;                         // B_bar row-major (512x32)
    BbarT[(long)u * 512 + dd] = h;      // B_bar^T (32x512)
  }
  if (id < 50 * 512) Cbf[id] = f2bf(Cin[id]);
  if (id < 50 * 32)  Ddt[id] = f2bf(Din[id] * dtp[0]);
}

// ---------------------------------------------------------------------------
// generic bf16 "bt" GEMM: C[m,n] = sum_k A[m,k]*Bt[n,k], bf16 out, batched z
// ---------------------------------------------------------------------------
template<int BM, int BN, int WM, int WN>
__global__ __launch_bounds__(256) void k_btgemm(
    const unsigned short* __restrict__ A, int ldA, long sAz,
    const unsigned short* __restrict__ Bt, int ldB, long sBz,
    unsigned short* __restrict__ C, int ldC, long sCz, int K){
  constexpr int FM = BM / (16 * WM), FN = BN / (16 * WN);
  __shared__ __align__(16) unsigned short As[BM * 32];
  __shared__ __align__(16) unsigned short Bs[BN * 32];
  int tid = threadIdx.x, wave = tid >> 6, lane = tid & 63;
  int wm = wave % WM, wn = wave / WM;
  long z = blockIdx.z;
  const unsigned short* Ab = A + z * sAz;
  const unsigned short* Bb = Bt + z * sBz;
  unsigned short* Cb = C + z * sCz;
  int m0 = blockIdx.y * BM, n0 = blockIdx.x * BN;
  int lr = lane & 15, kq = lane >> 4;
  f32x4 acc[FM][FN];
  f32x4 z4 = {0.f, 0.f, 0.f, 0.f};
  for (int i = 0; i < FM; i++) for (int j = 0; j < FN; j++) acc[i][j] = z4;
  for (int kt = 0; kt < K; kt += 32) {
    __syncthreads();
    for (int base = wave * 64; base < BM * 4; base += 256) {
      int cc = base + lane; int rr = cc >> 2, k8 = (cc & 3) << 3;
      gll16(Ab + (long)(m0 + rr) * ldA + kt + k8, As + base * 8);
    }
    for (int base = (wave ^ 2) * 64; base < BN * 4; base += 256) {
      int cc = base + lane; int rr = cc >> 2, k8 = (cc & 3) << 3;
      gll16(Bb + (long)(n0 + rr) * ldB + kt + k8, Bs + base * 8);
    }
    __syncthreads();
    bf16x8 af[FM], bfr[FN];
    for (int i = 0; i < FM; i++)
      af[i] = *(const bf16x8*)&As[(wm * (16 * FM) + i * 16 + lr) * 32 + kq * 8];
    for (int j = 0; j < FN; j++)
      bfr[j] = *(const bf16x8*)&Bs[(wn * (16 * FN) + j * 16 + lr) * 32 + kq * 8];
    for (int i = 0; i < FM; i++)
      for (int j = 0; j < FN; j++)
        acc[i][j] = __builtin_amdgcn_mfma_f32_16x16x32_bf16(af[i], bfr[j], acc[i][j], 0, 0, 0);
  }
  for (int i = 0; i < FM; i++)
    for (int j = 0; j < FN; j++) {
      int n = n0 + wn * (16 * FN) + j * 16 + lr;
      for (int r = 0; r < 4; r++) {
        int m = m0 + wm * (16 * FM) + i * 16 + kq * 4 + r;
        Cb[(long)m * ldC + n] = f2bf(acc[i][j][r]);
      }
    }
}

// batched 512x512 bf16 transpose: dst(ld512)[m][k] = src(ld1024)[k][m]
__global__ __launch_bounds__(256) void k_transpose512(
    const unsigned short* __restrict__ src, long sSz,
    unsigned short* __restrict__ dst, long sDz){
  long z = blockIdx.z;
  const unsigned short* S = src + z * sSz;
  unsigned short* D = dst + z * sDz;
  int id = blockIdx.x * 256 + threadIdx.x;
  int m = id >> 9, k = id & 511;
  D[(long)m * 512 + k] = S[(long)k * 1024 + m];
}

// fill U-region of WbigT: WbigT[n][512+32*(i-1)+uu] = G_{j-i}[dcol][uu] (i<=j)
__global__ __launch_bounds__(256) void k_assembleU(
    const unsigned short* __restrict__ G, unsigned short* __restrict__ WbigT){
  long id = (long)blockIdx.x * 256 + threadIdx.x;   // over 8192*512
  int n = (int)(id >> 9), kk2 = (int)(id & 511);
  int j = (n >> 9) + 1, dcol = n & 511;
  int i = (kk2 >> 5) + 1, uu = kk2 & 31;
  unsigned short v = 0;
  if (i <= j) v = G[(long)(j - i) * 16384 + dcol * 32 + uu];
  WbigT[(long)n * 1024 + 512 + kk2] = v;
}

// pack Xbuf: [Z0 bf16 (c=0 only) | U bf16 for all chunks]
__global__ __launch_bounds__(256) void k_packX(
    const float* __restrict__ zdyn, const float* __restrict__ U,
    unsigned short* __restrict__ Xbuf){
  long id = (long)blockIdx.x * 256 + threadIdx.x;   // over 16*512*1024
  long c = id >> 19;
  int rem = (int)(id & ((1 << 19) - 1));
  int b = rem >> 10, col = rem & 1023;
  if (col < 512) {
    if (c == 0) Xbuf[id] = f2bf(zdyn[(long)b * 512 + col]);
  } else {
    int kk2 = col - 512;
    int t = (int)(c * 16) + (kk2 >> 5), uu = kk2 & 31;
    Xbuf[id] = f2bf(U[((long)t * 512 + b) * 32 + uu]);
  }
}

// ---------------------------------------------------------------------------
// chunk GEMM: Z-block (512 x 8192) = Xc(512x1024) @ WbigT^T, BM=128 BN=64
// ---------------------------------------------------------------------------
__global__ __launch_bounds__(256) void k_chunk(
    const unsigned short* __restrict__ Xc, const unsigned short* __restrict__ WbigT,
    float* __restrict__ Zout, int t0, unsigned short* __restrict__ Xnext){
  __shared__ __align__(16) unsigned short As[128 * 32];
  __shared__ __align__(16) unsigned short Bs[64 * 32];
  int tid = threadIdx.x, wave = tid >> 6, lane = tid & 63;
  int wm = wave & 1, wn = wave >> 1;
  int m0 = blockIdx.y * 128;
  int n0 = blockIdx.x * 64;
  int lr = lane & 15, kq = lane >> 4;
  f32x4 acc[4][2];
  f32x4 z4 = {0.f, 0.f, 0.f, 0.f};
  for (int i = 0; i < 4; i++) for (int j = 0; j < 2; j++) acc[i][j] = z4;
  for (int kt = 0; kt < 1024; kt += 32) {
    __syncthreads();
    for (int base = wave * 64; base < 512; base += 256) {
      int cc = base + lane; int rr = cc >> 2, k8 = (cc & 3) << 3;
      gll16(Xc + (long)(m0 + rr) * 1024 + kt + k8, As + base * 8);
    }
    {
      int base = wave * 64;   // 256 chunks, one issue/wave
      int cc = base + lane; int rr = cc >> 2, k8 = (cc & 3) << 3;
      gll16(WbigT + (long)(n0 + rr) * 1024 + kt + k8, Bs + base * 8);
    }
    __syncthreads();
    bf16x8 af[4], bfr[2];
    for (int i = 0; i < 4; i++)
      af[i] = *(const bf16x8*)&As[(wm * 64 + i * 16 + lr) * 32 + kq * 8];
    for (int j = 0; j < 2; j++)
      bfr[j] = *(const bf16x8*)&Bs[(wn * 32 + j * 16 + lr) * 32 + kq * 8];
    for (int i = 0; i < 4; i++)
      for (int j = 0; j < 2; j++)
        acc[i][j] = __builtin_amdgcn_mfma_f32_16x16x32_bf16(af[i], bfr[j], acc[i][j], 0, 0, 0);
  }
  int jblk = n0 >> 9;
  int tt = t0 + jblk;
  bool wx = (Xnext != nullptr) && (jblk == 15);
  for (int j = 0; j < 2; j++) {
    int n = n0 + wn * 32 + j * 16 + lr;
    int dcol = n & 511;
    for (int i = 0; i < 4; i++)
      for (int r = 0; r < 4; r++) {
        int m = m0 + wm * 64 + i * 16 + kq * 4 + r;
        float v = acc[i][j][r];
        Zout[((long)tt * 512 + m) * 512 + dcol] = v;
        if (wx) Xnext[(long)m * 1024 + dcol] = f2bf(v);
      }
  }
}

// ---------------------------------------------------------------------------
// Y GEMM: Y[t,b,o] = sum_d Z[t,b,d]*C[o,d] + sum_u U[t,b,u]*(dt*D[o,u])
// ---------------------------------------------------------------------------
__global__ __launch_bounds__(256) void k_ygemm(
    const float* __restrict__ Zall, const unsigned short* __restrict__ Xbuf,
    const unsigned short* __restrict__ Cbf, const unsigned short* __restrict__ Ddt,
    float* __restrict__ Yout){
  __shared__ __align__(16) unsigned short As[128 * 32];
  __shared__ __align__(16) unsigned short Bs[64 * 32];
  int tid = threadIdx.x, wave = tid >> 6, lane = tid & 63;
  int wm = wave & 1, wn = wave >> 1;
  int b0 = blockIdx.x * 128;
  int t  = blockIdx.y;
  int lr = lane & 15, kq = lane >> 4;
  f32x4 acc[4][2];
  f32x4 z4 = {0.f, 0.f, 0.f, 0.f};
  for (int i = 0; i < 4; i++) for (int j = 0; j < 2; j++) acc[i][j] = z4;
  const float* Zt = Zall + ((long)t * 512 + b0) * 512;
  const unsigned short* Xu = Xbuf + (long)(t >> 4) * 524288 + (long)b0 * 1024 + 512 + (long)(t & 15) * 32;
  for (int kt = 0; kt < 17; kt++) {
    __syncthreads();
    if (kt < 16) {
      for (int f = tid; f < 1024; f += 256) {
        int rr = f >> 3, q = f & 7;
        float4 v = *(const float4*)(Zt + (long)rr * 512 + kt * 32 + q * 4);
        ushort4 h; h.x = f2bf(v.x); h.y = f2bf(v.y); h.z = f2bf(v.z); h.w = f2bf(v.w);
        *(ushort4*)&As[rr * 32 + q * 4] = h;
      }
      for (int f = tid; f < 512; f += 256) {
        int o = f >> 3, q = f & 7;
        ushort4 h = {0, 0, 0, 0};
        if (o < 50) h = *(const ushort4*)(Cbf + (long)o * 512 + kt * 32 + q * 4);
        *(ushort4*)&Bs[o * 32 + q * 4] = h;
      }
    } else {
      for (int f = tid; f < 1024; f += 256) {
        int rr = f >> 3, q = f & 7;
        ushort4 h = *(const ushort4*)(Xu + (long)rr * 1024 + q * 4);
        *(ushort4*)&As[rr * 32 + q * 4] = h;
      }
      for (int f = tid; f < 512; f += 256) {
        int o = f >> 3, q = f & 7;
        ushort4 h = {0, 0, 0, 0};
        if (o < 50) h = *(const ushort4*)(Ddt + (long)o * 32 + q * 4);
        *(ushort4*)&Bs[o * 32 + q * 4] = h;
      }
    }
    __syncthreads();
    bf16x8 af[4], bfr[2];
    for (int i = 0; i < 4; i++)
      af[i] = *(const bf16x8*)&As[(wm * 64 + i * 16 + lr) * 32 + kq * 8];
    for (int j = 0; j < 2; j++)
      bfr[j] = *(const bf16x8*)&Bs[(wn * 32 + j * 16 + lr) * 32 + kq * 8];
    for (int i = 0; i < 4; i++)
      for (int j = 0; j < 2; j++)
        acc[i][j] = __builtin_amdgcn_mfma_f32_16x16x32_bf16(af[i], bfr[j], acc[i][j], 0, 0, 0);
  }
  for (int j = 0; j < 2; j++) {
    int n = wn * 32 + j * 16 + lr;
    if (n >= 50) continue;
    for (int i = 0; i < 4; i++)
      for (int r = 0; r < 4; r++) {
        int b = b0 + wm * 64 + i * 16 + kq * 4 + r;
        Yout[((long)t * 512 + b) * 50 + n] = acc[i][j][r];
      }
  }
}

// ---------------------------------------------------------------------------
// workspace layout (bytes)
// ---------------------------------------------------------------------------
static constexpr long NE2F = 331776L * 4;   // 576^2 f32
static constexpr long SPLT = 995328L * 2;   // 576*1728 bf16
static constexpr long OFF_XF   = 0;
static constexpr long OFF_X2F  = OFF_XF   + NE2F;
static constexpr long OFF_X3F  = OFF_X2F  + NE2F;
static constexpr long OFF_B0F  = OFF_X3F  + NE2F;
static constexpr long OFF_B1F  = OFF_B0F  + NE2F;
static constexpr long OFF_XAP  = OFF_B1F  + NE2F;
static constexpr long OFF_XBT  = OFF_XAP  + SPLT;
static constexpr long OFF_X2AP = OFF_XBT  + SPLT;
static constexpr long OFF_X2BT = OFF_X2AP + SPLT;
static constexpr long OFF_X4BT = OFF_X2BT + SPLT;
static constexpr long OFF_B2AP = OFF_X4BT + SPLT;
static constexpr long OFF_TAP  = OFF_B2AP + SPLT;
static constexpr long OFF_EAP  = OFF_TAP  + SPLT;
static constexpr long OFF_EBT  = OFF_EAP  + SPLT;
static constexpr long OFF_FAP  = OFF_EBT  + SPLT;
static constexpr long OFF_FBT  = OFF_FAP  + SPLT;
static constexpr long OFF_EF   = OFF_FBT  + SPLT;
static constexpr long OFF_FF   = OFF_EF   + NE2F;   // 29,859,840
// region B aliases region A; only written after k_extract has consumed FF
static constexpr long OFF_WBT  = 0;                          // 16 MB
static constexpr long OFF_PT   = OFF_WBT + 8192L * 1024 * 2; // 16,777,216
static constexpr long OFF_BBT  = OFF_PT  + 8L * 262144 * 2;  // 20,971,520
static constexpr long OFF_G    = OFF_BBT + 32768;            // 21,004,288
static constexpr long OFF_CBF  = OFF_G   + 16L * 16384 * 2;  // 21,528,576
static constexpr long OFF_DDT  = OFF_CBF + 51200;            // 21,579,776
static constexpr long OFF_XB   = ((OFF_DDT + 3200 + 255) / 256) * 256; // 21,583,104
// total ws needed: OFF_XB + 16 MB = ~38.4 MB

extern "C" void kernel_launch(void* const* d_in, const int* in_sizes, int n_in,
                              void* d_out, int out_size, void* d_ws, size_t ws_size,
                              hipStream_t stream){
  const float* z_dyn = (const float*)d_in[0];
  const float* dtp   = (const float*)d_in[2];
  const float* U     = (const float*)d_in[3];
  const float* skew  = (const float*)d_in[4];
  const float* gamma = (const float*)d_in[5];
  const float* B_ct  = (const float*)d_in[6];
  const float* Cin   = (const float*)d_in[7];
  const float* Din   = (const float*)d_in[8];
  float* Zout = (float*)d_out;
  float* Yout = Zout + 67108864L;   // 256*512*512

  char* ws = (char*)d_ws;
  float* Xf  = (float*)(ws + OFF_XF);
  float* X2f = (float*)(ws + OFF_X2F);
  float* X3f = (float*)(ws + OFF_X3F);
  float* B0f = (float*)(ws + OFF_B0F);
  float* B1f = (float*)(ws + OFF_B1F);
  float* Ef  = (float*)(ws + OFF_EF);
  float* Ff  = (float*)(ws + OFF_FF);
  unsigned short* XAp  = (unsigned short*)(ws + OFF_XAP);
  unsigned short* XBt  = (unsigned short*)(ws + OFF_XBT);
  unsigned short* X2Ap = (unsigned short*)(ws + OFF_X2AP);
  unsigned short* X2Bt = (unsigned short*)(ws + OFF_X2BT);
  unsigned short* X4Bt = (unsigned short*)(ws + OFF_X4BT);
  unsigned short* B2Ap = (unsigned short*)(ws + OFF_B2AP);
  unsigned short* TAp  = (unsigned short*)(ws + OFF_TAP);
  unsigned short* EAp  = (unsigned short*)(ws + OFF_EAP);
  unsigned short* EBt  = (unsigned short*)(ws + OFF_EBT);
  unsigned short* FAp  = (unsigned short*)(ws + OFF_FAP);
  unsigned short* FBt  = (unsigned short*)(ws + OFF_FBT);
  unsigned short* WbigT = (unsigned short*)(ws + OFF_WBT);
  unsigned short* PT    = (unsigned short*)(ws + OFF_PT);
  unsigned short* BbarT = (unsigned short*)(ws + OFF_BBT);
  unsigned short* Gar   = (unsigned short*)(ws + OFF_G);
  unsigned short* Cbf   = (unsigned short*)(ws + OFF_CBF);
  unsigned short* Ddt   = (unsigned short*)(ws + OFF_DDT);
  unsigned short* Xb    = (unsigned short*)(ws + OFF_XB);

  dim3 b256(256);
  dim3 gE(18, 18);

  // ---- expm(Maug*dt) via scaling (s=5) + degree-11 PS Taylor ----
  k_build_M<<<dim3(1296), b256, 0, stream>>>(skew, gamma, dtp, B_ct, Xf, XAp, XBt);
  k_expm_gemm<<<gE, b256, 0, stream>>>(XAp,  XBt,  nullptr, X2f, X2Ap, X2Bt);   // X2 = X*X
  k_expm_gemm<<<gE, b256, 0, stream>>>(X2Ap, XBt,  nullptr, X3f, nullptr, nullptr); // X3 = X2*X
  k_expm_gemm<<<gE, b256, 0, stream>>>(X2Ap, X2Bt, nullptr, nullptr, nullptr, X4Bt); // X4 = X2*X2
  k_poly<<<dim3(1296), b256, 0, stream>>>(Xf, X2f, X3f, B0f, B1f, B2Ap);
  k_expm_gemm<<<gE, b256, 0, stream>>>(B2Ap, X4Bt, B1f, nullptr, TAp, nullptr);  // T = B2*X4+B1
  k_expm_gemm<<<gE, b256, 0, stream>>>(TAp,  X4Bt, B0f, Ef, EAp, EBt);           // E = T*X4+B0
  // 5 squarings (E<->F ping-pong), final in Ff
  k_expm_gemm<<<gE, b256, 0, stream>>>(EAp, EBt, nullptr, Ff, FAp, FBt);
  k_expm_gemm<<<gE, b256, 0, stream>>>(FAp, FBt, nullptr, Ef, EAp, EBt);
  k_expm_gemm<<<gE, b256, 0, stream>>>(EAp, EBt, nullptr, Ff, FAp, FBt);
  k_expm_gemm<<<gE, b256, 0, stream>>>(FAp, FBt, nullptr, Ef, EAp, EBt);
  k_expm_gemm<<<gE, b256, 0, stream>>>(EAp, EBt, nullptr, Ff, FAp, FBt);

  // ---- extract A_bar/B_bar, cast aux matrices ----
  k_extract<<<dim3(1024), b256, 0, stream>>>(Ff, Cin, Din, dtp, WbigT, PT, BbarT, Gar, Cbf, Ddt);

  // ---- powers of A by doubling: Apow_j stored as WbigT block j-1 (ld 1024)
  const long WBLK = 524288;  // 512*1024 elements
  const long PBLK = 262144;  // 512*512 elements
  k_btgemm<64,64,2,2><<<dim3(8,8,1), b256, 0, stream>>>(WbigT, 1024, 0, PT, 512, 0, WbigT + WBLK, 1024, 0, 512);           // Apow2
  k_transpose512<<<dim3(1024,1,1), b256, 0, stream>>>(WbigT + WBLK, WBLK, PT + PBLK, PBLK);                                 // PT2
  k_btgemm<64,64,2,2><<<dim3(8,8,2), b256, 0, stream>>>(WbigT + WBLK, 1024, 0, PT, 512, PBLK, WbigT + 2*WBLK, 1024, WBLK, 512); // Apow3,4
  k_transpose512<<<dim3(1024,1,2), b256, 0, stream>>>(WbigT + 2*WBLK, WBLK, PT + 2*PBLK, PBLK);                             // PT3,4
  k_btgemm<64,64,2,2><<<dim3(8,8,4), b256, 0, stream>>>(WbigT + 3*WBLK, 1024, 0, PT, 512, PBLK, WbigT + 4*WBLK, 1024, WBLK, 512); // Apow5..8
  k_transpose512<<<dim3(1024,1,4), b256, 0, stream>>>(WbigT + 4*WBLK, WBLK, PT + 4*PBLK, PBLK);                             // PT5..8
  k_btgemm<64,64,2,2><<<dim3(8,8,8), b256, 0, stream>>>(WbigT + 7*WBLK, 1024, 0, PT, 512, PBLK, WbigT + 8*WBLK, 1024, WBLK, 512); // Apow9..16
  // G_k = Apow_k * B_bar  (k=1..15), G_0 from extract
  k_btgemm<64,32,4,1><<<dim3(1,8,15), b256, 0, stream>>>(WbigT, 1024, WBLK, BbarT, 512, 0, Gar + 16384, 32, 16384, 512);

  // ---- assemble WbigT U-region, pack X buffers ----
  k_assembleU<<<dim3(16384), b256, 0, stream>>>(Gar, WbigT);
  k_packX<<<dim3(32768), b256, 0, stream>>>(z_dyn, U, Xb);

  // ---- 16 sequential chunk GEMMs ----
  for (int c = 0; c < 16; c++) {
    unsigned short* xn = (c < 15) ? (Xb + (long)(c + 1) * WBLK) : nullptr;
    k_chunk<<<dim3(128, 4), b256, 0, stream>>>(Xb + (long)c * WBLK, WbigT, Zout, 16 * c, xn);
  }

  // ---- Y pass ----
  k_ygemm<<<dim3(4, 256), b256, 0, stream>>>(Zout, Xb, Cbf, Ddt, Yout);
}